// Round 5
// baseline (233.100 us; speedup 1.0000x reference)
//
#include <hip/hip_runtime.h>
#include <stdint.h>

#define HIDDEN 512
#define NDRUG 2000
#define NREACT 10000
#define NEDGE 400000

// bucketed near-sort: 320 buckets x 32 cols each
#define NBKT 320
#define COLS_PER_BKT 32          // 10000/320 -> bucket = c >> 5 (c < 10240)
#define SLOT 2048                // capacity per bucket (mean 1250, sigma ~35; 2048 is ~+23 sigma)
#define BPB 6                    // edge-kernel blocks per bucket
#define EBLOCKS (NBKT * BPB)     // 1920

typedef __attribute__((ext_vector_type(8))) _Float16 f16x8;
typedef __attribute__((ext_vector_type(2))) _Float16 f16x2;
typedef __attribute__((ext_vector_type(4))) float f32x4;
typedef __attribute__((ext_vector_type(4))) float float4v;
typedef __attribute__((ext_vector_type(4))) _Float16 f16x4;

#if defined(__has_builtin)
#if __has_builtin(__builtin_amdgcn_fdot2)
#define HAVE_FDOT2 1
#endif
#endif

// ---------------- init cursors: cursor[b] = b*SLOT ----------------
__global__ __launch_bounds__(512) void init_cursor(int* __restrict__ cursor) {
  int i = threadIdx.x;
  if (i < NBKT) cursor[i] = i * SLOT;
}

// ---------------- fused setup: cast zd, cast zr, split W1, bucket-scatter edges ----------------
// block partition: [0,128) zd | [128,768) zr | [768,1024) W1 | [1024,1280) scatter
__global__ __launch_bounds__(256) void setup_kernel(
    const float* __restrict__ z_drug, const float* __restrict__ z_react,
    const float* __restrict__ W1,
    const int* __restrict__ row, const int* __restrict__ col,
    _Float16* __restrict__ zd_f, _Float16* __restrict__ zr_f,
    _Float16* __restrict__ WL, _Float16* __restrict__ WR,
    int* __restrict__ cursor, uint64_t* __restrict__ pk)
{
  const int b = blockIdx.x;
  if (b < 128) {
    const int nth = 128 * 256;
    const int NQ = NDRUG * HIDDEN / 4;
    for (int i = b * 256 + threadIdx.x; i < NQ; i += nth) {
      float4v v = *reinterpret_cast<const float4v*>(z_drug + (size_t)i * 4);
      f16x4 q; q[0]=(_Float16)v[0]; q[1]=(_Float16)v[1]; q[2]=(_Float16)v[2]; q[3]=(_Float16)v[3];
      *reinterpret_cast<f16x4*>(zd_f + (size_t)i * 4) = q;
    }
  } else if (b < 768) {
    const int nth = 640 * 256;
    const int NQ = NREACT * HIDDEN / 4;
    for (int i = (b - 128) * 256 + threadIdx.x; i < NQ; i += nth) {
      float4v v = *reinterpret_cast<const float4v*>(z_react + (size_t)i * 4);
      f16x4 q; q[0]=(_Float16)v[0]; q[1]=(_Float16)v[1]; q[2]=(_Float16)v[2]; q[3]=(_Float16)v[3];
      *reinterpret_cast<f16x4*>(zr_f + (size_t)i * 4) = q;
    }
  } else if (b < 1024) {
    const int nth = 256 * 256;
    const int NQ = HIDDEN * 2 * HIDDEN / 4;
    for (int i = (b - 768) * 256 + threadIdx.x; i < NQ; i += nth) {
      int e = i * 4;
      int o = e >> 10, j = e & 1023;
      float4v v = *reinterpret_cast<const float4v*>(W1 + e);
      f16x4 q; q[0]=(_Float16)v[0]; q[1]=(_Float16)v[1]; q[2]=(_Float16)v[2]; q[3]=(_Float16)v[3];
      if (j < HIDDEN) *reinterpret_cast<f16x4*>(WL + o * HIDDEN + j) = q;
      else            *reinterpret_cast<f16x4*>(WR + o * HIDDEN + (j - HIDDEN)) = q;
    }
  } else {
    // bucket scatter: pk[pos] = (src<<25) | (r<<14) | c   (44 bits used)
    const int nth = 256 * 256;
    for (int e = (b - 1024) * 256 + threadIdx.x; e < NEDGE; e += nth) {
      int c = col[e];
      int r = row[e];
      int bkt = c >> 5;                      // 0..312 (c<10000)
      int pos = atomicAdd(&cursor[bkt], 1);  // cursor pre-biased to bkt*SLOT
      pk[pos] = ((uint64_t)e << 25) | ((uint64_t)r << 14) | (uint64_t)c;
    }
  }
}

// ---------------- f16 MFMA GEMM, C[m][n] = sum_k A[m][k]*B[n][k] (+bias[n]) ----------------
#define BM 128
#define BN 128
#define BK 32

__global__ __launch_bounds__(256) void gemm_bt(
    const _Float16* __restrict__ Adrug, const _Float16* __restrict__ Areac,
    const _Float16* __restrict__ BL, const _Float16* __restrict__ BR,
    const float* __restrict__ bias,
    _Float16* __restrict__ Hd, _Float16* __restrict__ Hr)
{
  // flat grid: [0,64) -> drug panel (16 mb x 4 nb), [64,380) -> reaction (79 mb x 4 nb)
  const int bid = blockIdx.x;
  const int z = (bid >= 64) ? 1 : 0;
  const int t = z ? bid - 64 : bid;
  const int mb = t >> 2;
  const int nb = t & 3;
  const int M = (z == 0) ? NDRUG : NREACT;
  const _Float16* A = (z == 0) ? Adrug : Areac;
  const _Float16* B = (z == 0) ? BL : BR;
  _Float16* C = (z == 0) ? Hd : Hr;
  const bool has_bias = (z == 0);
  const int K = HIDDEN, N = HIDDEN;

  __shared__ _Float16 As[BM * BK];
  __shared__ _Float16 Bs[BN * BK];

  const int tid = threadIdx.x;
  const int lane = tid & 63;
  const int wid = tid >> 6;
  const int wm = wid >> 1;
  const int wn = wid & 1;

  f32x4 acc[4][4];
#pragma unroll
  for (int i = 0; i < 4; ++i)
#pragma unroll
    for (int j = 0; j < 4; ++j) acc[i][j] = (f32x4){0.f, 0.f, 0.f, 0.f};

  const int row0 = mb * BM;
  const int col0 = nb * BN;
  const int srow = lane >> 2;
  const int scol = (lane & 3) * 8;

  for (int kt = 0; kt < K; kt += BK) {
#pragma unroll
    for (int i = 0; i < 2; ++i) {
      int rA = row0 + wid * 32 + i * 16 + srow;
      rA = rA < M ? rA : M - 1;
      const _Float16* gA = A + (size_t)rA * K + kt + scol;
      _Float16* lA = As + (wid * 32 + i * 16) * BK;
      __builtin_amdgcn_global_load_lds(
          (const __attribute__((address_space(1))) void*)gA,
          (__attribute__((address_space(3))) void*)lA, 16, 0, 0);
      int rB = col0 + wid * 32 + i * 16 + srow;
      const _Float16* gB = B + (size_t)rB * K + kt + scol;
      _Float16* lB = Bs + (wid * 32 + i * 16) * BK;
      __builtin_amdgcn_global_load_lds(
          (const __attribute__((address_space(1))) void*)gB,
          (__attribute__((address_space(3))) void*)lB, 16, 0, 0);
    }
    __syncthreads();

    const int fr = lane & 15;
    const int kg = (lane >> 4) * 8;
    f16x8 af[4], bfr[4];
#pragma unroll
    for (int mi = 0; mi < 4; ++mi)
      af[mi] = *reinterpret_cast<const f16x8*>(As + (wm * 64 + mi * 16 + fr) * BK + kg);
#pragma unroll
    for (int ni = 0; ni < 4; ++ni)
      bfr[ni] = *reinterpret_cast<const f16x8*>(Bs + (wn * 64 + ni * 16 + fr) * BK + kg);
#pragma unroll
    for (int mi = 0; mi < 4; ++mi)
#pragma unroll
      for (int ni = 0; ni < 4; ++ni)
        acc[mi][ni] = __builtin_amdgcn_mfma_f32_16x16x32_f16(af[mi], bfr[ni], acc[mi][ni], 0, 0, 0);
    __syncthreads();
  }

  const int crow = (lane >> 4) * 4;
  const int ccol = lane & 15;
#pragma unroll
  for (int ni = 0; ni < 4; ++ni) {
    const int gc = col0 + wn * 64 + ni * 16 + ccol;
    const float bv = has_bias ? bias[gc] : 0.0f;
#pragma unroll
    for (int mi = 0; mi < 4; ++mi) {
#pragma unroll
      for (int j = 0; j < 4; ++j) {
        const int gr = row0 + wm * 64 + mi * 16 + crow + j;
        if (gr < M) C[(size_t)gr * N + gc] = (_Float16)(acc[mi][ni][j] + bv);
      }
    }
  }
}

// ---------------- edge kernel: bucketed regions, 2 edges per 16-lane group ----------------
__global__ __launch_bounds__(256) void edge_kernel(
    const _Float16* __restrict__ Hd, const _Float16* __restrict__ Hr,
    const uint64_t* __restrict__ pk, const int* __restrict__ cursor,
    const float* __restrict__ W2, const float* __restrict__ b2,
    float* __restrict__ out)
{
  // bucket->XCD chunked mapping: XCD x owns buckets [x*40, x*40+40) -> Hr slice 1.3MB + Hd 2MB in L2
  const int bid = blockIdx.x;
  const int xcd = bid & 7;
  const int idx = bid >> 3;              // 0..239
  const int bucket = xcd * 40 + idx / BPB;
  const int slice = idx % BPB;
  const int base = bucket * SLOT;
  const int count = cursor[bucket] - base;   // cursor was pre-biased
  const int per = (count + BPB - 1) / BPB;
  const int s = slice * per;
  const int e_end = (s + per < count) ? s + per : count;
  if (s >= e_end) return;

  const int lane = threadIdx.x & 63;
  const int li = lane & 15;
  const int g = lane >> 4;
  const int wv = threadIdx.x >> 6;       // 0..3

  // W2 fragment: lane covers elems li*8 + 128k
  f16x8 w2v[4];
#pragma unroll
  for (int k = 0; k < 4; ++k) {
    const float* p = W2 + li * 8 + k * 128;
    f16x8 q;
#pragma unroll
    for (int j = 0; j < 8; ++j) q[j] = (_Float16)p[j];
    w2v[k] = q;
  }
  const float bias2 = *b2;
  const f16x8 zero8 = (f16x8)(_Float16)0;

  // per iter: 4 waves x 4 groups x 2 edges = 32 edges/block
  for (int ep0 = s + (wv * 4 + g) * 2; ep0 < e_end; ep0 += 32) {
    const int ep1 = (ep0 + 1 < e_end) ? ep0 + 1 : ep0;   // tail dup, benign
    const uint64_t p0 = pk[base + ep0];
    const uint64_t p1 = pk[base + ep1];
    const int c0 = (int)(p0 & 0x3FFF), r0 = (int)((p0 >> 14) & 0x7FF), s0i = (int)(p0 >> 25);
    const int c1 = (int)(p1 & 0x3FFF), r1 = (int)((p1 >> 14) & 0x7FF), s1i = (int)(p1 >> 25);
    const _Float16* hd0 = Hd + (size_t)r0 * HIDDEN;
    const _Float16* hr0 = Hr + (size_t)c0 * HIDDEN;
    const _Float16* hd1 = Hd + (size_t)r1 * HIDDEN;
    const _Float16* hr1 = Hr + (size_t)c1 * HIDDEN;
    float acc0 = 0.f, acc1 = 0.f;
#pragma unroll
    for (int k = 0; k < 4; ++k) {
      const int o = li * 8 + k * 128;
      f16x8 vd0 = *reinterpret_cast<const f16x8*>(hd0 + o);
      f16x8 vr0 = *reinterpret_cast<const f16x8*>(hr0 + o);
      f16x8 vd1 = *reinterpret_cast<const f16x8*>(hd1 + o);
      f16x8 vr1 = *reinterpret_cast<const f16x8*>(hr1 + o);
      f16x8 t0 = __builtin_elementwise_max(vd0 + vr0, zero8);
      f16x8 t1 = __builtin_elementwise_max(vd1 + vr1, zero8);
#if defined(HAVE_FDOT2)
#pragma unroll
      for (int j = 0; j < 4; ++j) {
        f16x2 wp = {w2v[k][2 * j], w2v[k][2 * j + 1]};
        f16x2 sp0 = {t0[2 * j], t0[2 * j + 1]};
        f16x2 sp1 = {t1[2 * j], t1[2 * j + 1]};
        acc0 = __builtin_amdgcn_fdot2(sp0, wp, acc0, false);
        acc1 = __builtin_amdgcn_fdot2(sp1, wp, acc1, false);
      }
#else
#pragma unroll
      for (int j = 0; j < 8; ++j) {
        acc0 += (float)t0[j] * (float)w2v[k][j];
        acc1 += (float)t1[j] * (float)w2v[k][j];
      }
#endif
    }
#pragma unroll
    for (int off = 8; off >= 1; off >>= 1) {
      acc0 += __shfl_xor(acc0, off);
      acc1 += __shfl_xor(acc1, off);
    }
    if (li == 0) {
      out[s0i] = acc0 + bias2;
      out[s1i] = acc1 + bias2;
    }
  }
}

extern "C" void kernel_launch(void* const* d_in, const int* in_sizes, int n_in,
                              void* d_out, int out_size, void* d_ws, size_t ws_size,
                              hipStream_t stream) {
  const float* z_drug  = (const float*)d_in[0];
  const float* z_react = (const float*)d_in[1];
  const int*   row     = (const int*)d_in[2];
  const int*   col     = (const int*)d_in[3];
  const float* W1      = (const float*)d_in[4];
  const float* b1      = (const float*)d_in[5];
  const float* W2      = (const float*)d_in[6];
  const float* b2      = (const float*)d_in[7];
  float* out = (float*)d_out;

  char* ws = (char*)d_ws;
  size_t off = 0;
  auto alloc = [&](size_t bytes) {
    void* p = ws + off;
    off += (bytes + 255) & ~(size_t)255;
    return p;
  };
  _Float16* zd_f = (_Float16*)alloc((size_t)NDRUG * HIDDEN * 2);
  _Float16* zr_f = (_Float16*)alloc((size_t)NREACT * HIDDEN * 2);
  _Float16* wl_f = (_Float16*)alloc((size_t)HIDDEN * HIDDEN * 2);
  _Float16* wr_f = (_Float16*)alloc((size_t)HIDDEN * HIDDEN * 2);
  _Float16* Hd   = (_Float16*)alloc((size_t)NDRUG * HIDDEN * 2);
  _Float16* Hr   = (_Float16*)alloc((size_t)NREACT * HIDDEN * 2);
  int*      cursor = (int*)alloc(NBKT * 4);
  uint64_t* pk     = (uint64_t*)alloc((size_t)NBKT * SLOT * 8);  // 5.2 MB

  init_cursor<<<1, 512, 0, stream>>>(cursor);
  setup_kernel<<<1280, 256, 0, stream>>>(z_drug, z_react, W1, row, col,
                                         zd_f, zr_f, wl_f, wr_f, cursor, pk);
  gemm_bt<<<380, 256, 0, stream>>>(zd_f, zr_f, wl_f, wr_f, b1, Hd, Hr);
  edge_kernel<<<EBLOCKS, 256, 0, stream>>>(Hd, Hr, pk, cursor, W2, b2, out);
}

// Round 6
// 85.737 us; speedup vs baseline: 2.7188x; 2.7188x over previous
//
#include <hip/hip_runtime.h>
#include <stdint.h>

#define HIDDEN 512
#define NDRUG 2000
#define NREACT 10000
#define NEDGE 400000

// bucketed near-sort: 313 used buckets x 32 cols each (c>>5), padded to 320
#define NBKT 320
#define SLOT 2048                 // capacity per bucket (mean ~1280, sigma ~36)
#define CSTRIDE 16                // cursor padded to 1 int per 64B cache line
#define BPB 6                     // edge-kernel blocks per bucket
#define EBLOCKS (NBKT * BPB)      // 1920
#define NSCAT 128                 // scatter blocks (LDS-aggregated)
#define EPB ((NEDGE + NSCAT - 1) / NSCAT)   // 3125 edges per scatter block

typedef __attribute__((ext_vector_type(8))) _Float16 f16x8;
typedef __attribute__((ext_vector_type(2))) _Float16 f16x2;
typedef __attribute__((ext_vector_type(4))) float f32x4;
typedef __attribute__((ext_vector_type(4))) float float4v;
typedef __attribute__((ext_vector_type(4))) _Float16 f16x4;

#if defined(__has_builtin)
#if __has_builtin(__builtin_amdgcn_fdot2)
#define HAVE_FDOT2 1
#endif
#endif

// ---------------- init padded cursors: cursor[b*CSTRIDE] = b*SLOT ----------------
__global__ __launch_bounds__(256) void init_cursor(int* __restrict__ cursor) {
  int i = blockIdx.x * blockDim.x + threadIdx.x;
  if (i < NBKT) cursor[i * CSTRIDE] = i * SLOT;
}

// ---------------- fused setup: cast zd, cast zr, split W1, LDS-aggregated bucket scatter ----
// block partition: [0,128) zd | [128,768) zr | [768,1024) W1 | [1024,1024+NSCAT) scatter
__global__ __launch_bounds__(256) void setup_kernel(
    const float* __restrict__ z_drug, const float* __restrict__ z_react,
    const float* __restrict__ W1,
    const int* __restrict__ row, const int* __restrict__ col,
    _Float16* __restrict__ zd_f, _Float16* __restrict__ zr_f,
    _Float16* __restrict__ WL, _Float16* __restrict__ WR,
    int* __restrict__ cursor, uint64_t* __restrict__ pk)
{
  __shared__ int lhist[NBKT];
  __shared__ int lbase[NBKT];
  const int b = blockIdx.x;
  const int tid = threadIdx.x;
  if (b < 128) {
    const int nth = 128 * 256;
    const int NQ = NDRUG * HIDDEN / 4;
    for (int i = b * 256 + tid; i < NQ; i += nth) {
      float4v v = *reinterpret_cast<const float4v*>(z_drug + (size_t)i * 4);
      f16x4 q; q[0]=(_Float16)v[0]; q[1]=(_Float16)v[1]; q[2]=(_Float16)v[2]; q[3]=(_Float16)v[3];
      *reinterpret_cast<f16x4*>(zd_f + (size_t)i * 4) = q;
    }
  } else if (b < 768) {
    const int nth = 640 * 256;
    const int NQ = NREACT * HIDDEN / 4;
    for (int i = (b - 128) * 256 + tid; i < NQ; i += nth) {
      float4v v = *reinterpret_cast<const float4v*>(z_react + (size_t)i * 4);
      f16x4 q; q[0]=(_Float16)v[0]; q[1]=(_Float16)v[1]; q[2]=(_Float16)v[2]; q[3]=(_Float16)v[3];
      *reinterpret_cast<f16x4*>(zr_f + (size_t)i * 4) = q;
    }
  } else if (b < 1024) {
    const int nth = 256 * 256;
    const int NQ = HIDDEN * 2 * HIDDEN / 4;
    for (int i = (b - 768) * 256 + tid; i < NQ; i += nth) {
      int e = i * 4;
      int o = e >> 10, j = e & 1023;
      float4v v = *reinterpret_cast<const float4v*>(W1 + e);
      f16x4 q; q[0]=(_Float16)v[0]; q[1]=(_Float16)v[1]; q[2]=(_Float16)v[2]; q[3]=(_Float16)v[3];
      if (j < HIDDEN) *reinterpret_cast<f16x4*>(WL + o * HIDDEN + j) = q;
      else            *reinterpret_cast<f16x4*>(WR + o * HIDDEN + (j - HIDDEN)) = q;
    }
  } else {
    // LDS-aggregated bucket scatter. Block handles edges [e0, e1).
    const int sb = b - 1024;
    const int e0 = sb * EPB;
    const int e1 = (e0 + EPB < NEDGE) ? e0 + EPB : NEDGE;
    for (int i = tid; i < NBKT; i += 256) lhist[i] = 0;
    __syncthreads();
    for (int e = e0 + tid; e < e1; e += 256)
      atomicAdd(&lhist[col[e] >> 5], 1);
    __syncthreads();
    for (int i = tid; i < NBKT; i += 256) {
      int cnt = lhist[i];
      lbase[i] = cnt ? atomicAdd(&cursor[i * CSTRIDE], cnt) : 0;  // reserve range (padded line)
      lhist[i] = 0;                                               // reuse as local offset
    }
    __syncthreads();
    for (int e = e0 + tid; e < e1; e += 256) {
      int c = col[e];
      int r = row[e];
      int bkt = c >> 5;
      int lo = atomicAdd(&lhist[bkt], 1);
      pk[lbase[bkt] + lo] = ((uint64_t)e << 25) | ((uint64_t)r << 14) | (uint64_t)c;
    }
  }
}

// ---------------- f16 MFMA GEMM, C[m][n] = sum_k A[m][k]*B[n][k] (+bias[n]) ----------------
#define BM 128
#define BN 128
#define BK 32

__global__ __launch_bounds__(256) void gemm_bt(
    const _Float16* __restrict__ Adrug, const _Float16* __restrict__ Areac,
    const _Float16* __restrict__ BL, const _Float16* __restrict__ BR,
    const float* __restrict__ bias,
    _Float16* __restrict__ Hd, _Float16* __restrict__ Hr)
{
  // flat grid: [0,64) -> drug panel (16 mb x 4 nb), [64,380) -> reaction (79 mb x 4 nb)
  const int bid = blockIdx.x;
  const int z = (bid >= 64) ? 1 : 0;
  const int t = z ? bid - 64 : bid;
  const int mb = t >> 2;
  const int nb = t & 3;
  const int M = (z == 0) ? NDRUG : NREACT;
  const _Float16* A = (z == 0) ? Adrug : Areac;
  const _Float16* B = (z == 0) ? BL : BR;
  _Float16* C = (z == 0) ? Hd : Hr;
  const bool has_bias = (z == 0);
  const int K = HIDDEN, N = HIDDEN;

  __shared__ _Float16 As[BM * BK];
  __shared__ _Float16 Bs[BN * BK];

  const int tid = threadIdx.x;
  const int lane = tid & 63;
  const int wid = tid >> 6;
  const int wm = wid >> 1;
  const int wn = wid & 1;

  f32x4 acc[4][4];
#pragma unroll
  for (int i = 0; i < 4; ++i)
#pragma unroll
    for (int j = 0; j < 4; ++j) acc[i][j] = (f32x4){0.f, 0.f, 0.f, 0.f};

  const int row0 = mb * BM;
  const int col0 = nb * BN;
  const int srow = lane >> 2;
  const int scol = (lane & 3) * 8;

  for (int kt = 0; kt < K; kt += BK) {
#pragma unroll
    for (int i = 0; i < 2; ++i) {
      int rA = row0 + wid * 32 + i * 16 + srow;
      rA = rA < M ? rA : M - 1;
      const _Float16* gA = A + (size_t)rA * K + kt + scol;
      _Float16* lA = As + (wid * 32 + i * 16) * BK;
      __builtin_amdgcn_global_load_lds(
          (const __attribute__((address_space(1))) void*)gA,
          (__attribute__((address_space(3))) void*)lA, 16, 0, 0);
      int rB = col0 + wid * 32 + i * 16 + srow;
      const _Float16* gB = B + (size_t)rB * K + kt + scol;
      _Float16* lB = Bs + (wid * 32 + i * 16) * BK;
      __builtin_amdgcn_global_load_lds(
          (const __attribute__((address_space(1))) void*)gB,
          (__attribute__((address_space(3))) void*)lB, 16, 0, 0);
    }
    __syncthreads();

    const int fr = lane & 15;
    const int kg = (lane >> 4) * 8;
    f16x8 af[4], bfr[4];
#pragma unroll
    for (int mi = 0; mi < 4; ++mi)
      af[mi] = *reinterpret_cast<const f16x8*>(As + (wm * 64 + mi * 16 + fr) * BK + kg);
#pragma unroll
    for (int ni = 0; ni < 4; ++ni)
      bfr[ni] = *reinterpret_cast<const f16x8*>(Bs + (wn * 64 + ni * 16 + fr) * BK + kg);
#pragma unroll
    for (int mi = 0; mi < 4; ++mi)
#pragma unroll
      for (int ni = 0; ni < 4; ++ni)
        acc[mi][ni] = __builtin_amdgcn_mfma_f32_16x16x32_f16(af[mi], bfr[ni], acc[mi][ni], 0, 0, 0);
    __syncthreads();
  }

  const int crow = (lane >> 4) * 4;
  const int ccol = lane & 15;
#pragma unroll
  for (int ni = 0; ni < 4; ++ni) {
    const int gc = col0 + wn * 64 + ni * 16 + ccol;
    const float bv = has_bias ? bias[gc] : 0.0f;
#pragma unroll
    for (int mi = 0; mi < 4; ++mi) {
#pragma unroll
      for (int j = 0; j < 4; ++j) {
        const int gr = row0 + wm * 64 + mi * 16 + crow + j;
        if (gr < M) C[(size_t)gr * N + gc] = (_Float16)(acc[mi][ni][j] + bv);
      }
    }
  }
}

// ---------------- edge kernel: bucketed regions, 4 edges per 16-lane group ----------------
__global__ __launch_bounds__(256) void edge_kernel(
    const _Float16* __restrict__ Hd, const _Float16* __restrict__ Hr,
    const uint64_t* __restrict__ pk, const int* __restrict__ cursor,
    const float* __restrict__ W2, const float* __restrict__ b2,
    float* __restrict__ out)
{
  // bucket->XCD chunked mapping: XCD x owns buckets [x*40, x*40+40) -> Hr slice 1.25MB + Hd 2MB in L2
  const int bid = blockIdx.x;
  const int xcd = bid & 7;
  const int idx = bid >> 3;              // 0..239
  const int bucket = xcd * 40 + idx / BPB;
  const int slice = idx % BPB;
  const int base = bucket * SLOT;
  const int count = cursor[bucket * CSTRIDE] - base;   // cursor was pre-biased
  const int per = (count + BPB - 1) / BPB;
  const int s = slice * per;
  const int e_end = (s + per < count) ? s + per : count;
  if (s >= e_end) return;

  const int lane = threadIdx.x & 63;
  const int li = lane & 15;
  const int g = lane >> 4;
  const int wv = threadIdx.x >> 6;       // 0..3

  // W2 fragment: lane covers elems li*8 + 128k
  f16x8 w2v[4];
#pragma unroll
  for (int k = 0; k < 4; ++k) {
    const float* p = W2 + li * 8 + k * 128;
    f16x8 q;
#pragma unroll
    for (int j = 0; j < 8; ++j) q[j] = (_Float16)p[j];
    w2v[k] = q;
  }
  const float bias2 = *b2;
  const f16x8 zero8 = (f16x8)(_Float16)0;

  // per iter: 4 waves x 4 groups x 4 edges = 64 edges/block
  for (int ep0 = s + (wv * 4 + g) * 4; ep0 < e_end; ep0 += 64) {
    int ep[4];
#pragma unroll
    for (int j = 0; j < 4; ++j) {
      int t = ep0 + j;
      ep[j] = (t < e_end) ? t : e_end - 1;   // tail dup, benign (same value rewritten)
    }
    uint64_t p[4];
#pragma unroll
    for (int j = 0; j < 4; ++j) p[j] = pk[base + ep[j]];
    const _Float16* hd[4];
    const _Float16* hr[4];
    int si[4];
#pragma unroll
    for (int j = 0; j < 4; ++j) {
      int c = (int)(p[j] & 0x3FFF);
      int r = (int)((p[j] >> 14) & 0x7FF);
      si[j] = (int)(p[j] >> 25);
      hd[j] = Hd + (size_t)r * HIDDEN;
      hr[j] = Hr + (size_t)c * HIDDEN;
    }
    float acc[4] = {0.f, 0.f, 0.f, 0.f};
#pragma unroll
    for (int k = 0; k < 4; ++k) {
      const int o = li * 8 + k * 128;
      f16x8 vd[4], vr[4];
#pragma unroll
      for (int j = 0; j < 4; ++j) {
        vd[j] = *reinterpret_cast<const f16x8*>(hd[j] + o);
        vr[j] = *reinterpret_cast<const f16x8*>(hr[j] + o);
      }
#pragma unroll
      for (int j = 0; j < 4; ++j) {
        f16x8 t = __builtin_elementwise_max(vd[j] + vr[j], zero8);
#if defined(HAVE_FDOT2)
#pragma unroll
        for (int q = 0; q < 4; ++q) {
          f16x2 wp = {w2v[k][2 * q], w2v[k][2 * q + 1]};
          f16x2 sp = {t[2 * q], t[2 * q + 1]};
          acc[j] = __builtin_amdgcn_fdot2(sp, wp, acc[j], false);
        }
#else
#pragma unroll
        for (int q = 0; q < 8; ++q)
          acc[j] += (float)t[q] * (float)w2v[k][q];
#endif
      }
    }
#pragma unroll
    for (int off = 8; off >= 1; off >>= 1) {
#pragma unroll
      for (int j = 0; j < 4; ++j) acc[j] += __shfl_xor(acc[j], off);
    }
    if (li == 0) {
#pragma unroll
      for (int j = 0; j < 4; ++j) out[si[j]] = acc[j] + bias2;
    }
  }
}

extern "C" void kernel_launch(void* const* d_in, const int* in_sizes, int n_in,
                              void* d_out, int out_size, void* d_ws, size_t ws_size,
                              hipStream_t stream) {
  const float* z_drug  = (const float*)d_in[0];
  const float* z_react = (const float*)d_in[1];
  const int*   row     = (const int*)d_in[2];
  const int*   col     = (const int*)d_in[3];
  const float* W1      = (const float*)d_in[4];
  const float* b1      = (const float*)d_in[5];
  const float* W2      = (const float*)d_in[6];
  const float* b2      = (const float*)d_in[7];
  float* out = (float*)d_out;

  char* ws = (char*)d_ws;
  size_t off = 0;
  auto alloc = [&](size_t bytes) {
    void* p = ws + off;
    off += (bytes + 255) & ~(size_t)255;
    return p;
  };
  _Float16* zd_f = (_Float16*)alloc((size_t)NDRUG * HIDDEN * 2);
  _Float16* zr_f = (_Float16*)alloc((size_t)NREACT * HIDDEN * 2);
  _Float16* wl_f = (_Float16*)alloc((size_t)HIDDEN * HIDDEN * 2);
  _Float16* wr_f = (_Float16*)alloc((size_t)HIDDEN * HIDDEN * 2);
  _Float16* Hd   = (_Float16*)alloc((size_t)NDRUG * HIDDEN * 2);
  _Float16* Hr   = (_Float16*)alloc((size_t)NREACT * HIDDEN * 2);
  int*      cursor = (int*)alloc((size_t)NBKT * CSTRIDE * 4);       // 20 KB padded
  uint64_t* pk     = (uint64_t*)alloc((size_t)NBKT * SLOT * 8);     // 5.2 MB

  init_cursor<<<2, 256, 0, stream>>>(cursor);
  setup_kernel<<<1024 + NSCAT, 256, 0, stream>>>(z_drug, z_react, W1, row, col,
                                                 zd_f, zr_f, wl_f, wr_f, cursor, pk);
  gemm_bt<<<380, 256, 0, stream>>>(zd_f, zr_f, wl_f, wr_f, b1, Hd, Hr);
  edge_kernel<<<EBLOCKS, 256, 0, stream>>>(Hd, Hr, pk, cursor, W2, b2, out);
}

// Round 7
// 78.193 us; speedup vs baseline: 2.9811x; 1.0965x over previous
//
#include <hip/hip_runtime.h>
#include <stdint.h>

#define HIDDEN 512
#define NDRUG 2000
#define NREACT 10000
#define NEDGE 400000

// bucketed near-sort: 313 used buckets x 32 cols each (c>>5), padded to 320
#define NBKT 320
#define SLOT 2048                 // capacity per bucket (mean ~1280, sigma ~36; +21 sigma)
#define CSTRIDE 16                // cursor padded to 1 int per 64B cache line
#define NSCAT 128                 // scatter blocks (LDS-aggregated)
#define EPB ((NEDGE + NSCAT - 1) / NSCAT)   // 3125 edges per scatter block

// edge kernel v2: 2 blocks per bucket, in-LDS col sort + Hr in LDS
#define BPB2 2
#define EBLK (NBKT * BPB2)        // 640
#define MAXSL 1024                // max slice entries = ceil(SLOT/BPB2)
#define HRSTRIDE 520              // f16 elems per LDS hr row (512 + 8 pad)

typedef __attribute__((ext_vector_type(8))) _Float16 f16x8;
typedef __attribute__((ext_vector_type(2))) _Float16 f16x2;
typedef __attribute__((ext_vector_type(4))) float f32x4;
typedef __attribute__((ext_vector_type(4))) float float4v;
typedef __attribute__((ext_vector_type(4))) _Float16 f16x4;

#if defined(__has_builtin)
#if __has_builtin(__builtin_amdgcn_fdot2)
#define HAVE_FDOT2 1
#endif
#endif

// ---------------- init padded cursors: cursor[b*CSTRIDE] = b*SLOT ----------------
__global__ __launch_bounds__(256) void init_cursor(int* __restrict__ cursor) {
  int i = blockIdx.x * blockDim.x + threadIdx.x;
  if (i < NBKT) cursor[i * CSTRIDE] = i * SLOT;
}

// ---------------- fused setup: cast zd, cast zr, split W1, LDS-aggregated bucket scatter ----
// block partition: [0,128) zd | [128,768) zr | [768,1024) W1 | [1024,1024+NSCAT) scatter
__global__ __launch_bounds__(256) void setup_kernel(
    const float* __restrict__ z_drug, const float* __restrict__ z_react,
    const float* __restrict__ W1,
    const int* __restrict__ row, const int* __restrict__ col,
    _Float16* __restrict__ zd_f, _Float16* __restrict__ zr_f,
    _Float16* __restrict__ WL, _Float16* __restrict__ WR,
    int* __restrict__ cursor, uint64_t* __restrict__ pk)
{
  __shared__ int lhist[NBKT];
  __shared__ int lbase[NBKT];
  const int b = blockIdx.x;
  const int tid = threadIdx.x;
  if (b < 128) {
    const int nth = 128 * 256;
    const int NQ = NDRUG * HIDDEN / 4;
    for (int i = b * 256 + tid; i < NQ; i += nth) {
      float4v v = *reinterpret_cast<const float4v*>(z_drug + (size_t)i * 4);
      f16x4 q; q[0]=(_Float16)v[0]; q[1]=(_Float16)v[1]; q[2]=(_Float16)v[2]; q[3]=(_Float16)v[3];
      *reinterpret_cast<f16x4*>(zd_f + (size_t)i * 4) = q;
    }
  } else if (b < 768) {
    const int nth = 640 * 256;
    const int NQ = NREACT * HIDDEN / 4;
    for (int i = (b - 128) * 256 + tid; i < NQ; i += nth) {
      float4v v = *reinterpret_cast<const float4v*>(z_react + (size_t)i * 4);
      f16x4 q; q[0]=(_Float16)v[0]; q[1]=(_Float16)v[1]; q[2]=(_Float16)v[2]; q[3]=(_Float16)v[3];
      *reinterpret_cast<f16x4*>(zr_f + (size_t)i * 4) = q;
    }
  } else if (b < 1024) {
    const int nth = 256 * 256;
    const int NQ = HIDDEN * 2 * HIDDEN / 4;
    for (int i = (b - 768) * 256 + tid; i < NQ; i += nth) {
      int e = i * 4;
      int o = e >> 10, j = e & 1023;
      float4v v = *reinterpret_cast<const float4v*>(W1 + e);
      f16x4 q; q[0]=(_Float16)v[0]; q[1]=(_Float16)v[1]; q[2]=(_Float16)v[2]; q[3]=(_Float16)v[3];
      if (j < HIDDEN) *reinterpret_cast<f16x4*>(WL + o * HIDDEN + j) = q;
      else            *reinterpret_cast<f16x4*>(WR + o * HIDDEN + (j - HIDDEN)) = q;
    }
  } else {
    // LDS-aggregated bucket scatter. Block handles edges [e0, e1).
    const int sb = b - 1024;
    const int e0 = sb * EPB;
    const int e1 = (e0 + EPB < NEDGE) ? e0 + EPB : NEDGE;
    for (int i = tid; i < NBKT; i += 256) lhist[i] = 0;
    __syncthreads();
    for (int e = e0 + tid; e < e1; e += 256)
      atomicAdd(&lhist[col[e] >> 5], 1);
    __syncthreads();
    for (int i = tid; i < NBKT; i += 256) {
      int cnt = lhist[i];
      lbase[i] = cnt ? atomicAdd(&cursor[i * CSTRIDE], cnt) : 0;  // reserve range (padded line)
      lhist[i] = 0;                                               // reuse as local offset
    }
    __syncthreads();
    for (int e = e0 + tid; e < e1; e += 256) {
      int c = col[e];
      int r = row[e];
      int bkt = c >> 5;
      int lo = atomicAdd(&lhist[bkt], 1);
      pk[lbase[bkt] + lo] = ((uint64_t)e << 25) | ((uint64_t)r << 14) | (uint64_t)c;
    }
  }
}

// ---------------- f16 MFMA GEMM, C[m][n] = sum_k A[m][k]*B[n][k] (+bias[n]) ----------------
#define BM 128
#define BN 128
#define BK 32

__global__ __launch_bounds__(256) void gemm_bt(
    const _Float16* __restrict__ Adrug, const _Float16* __restrict__ Areac,
    const _Float16* __restrict__ BL, const _Float16* __restrict__ BR,
    const float* __restrict__ bias,
    _Float16* __restrict__ Hd, _Float16* __restrict__ Hr)
{
  // flat grid: [0,64) -> drug panel (16 mb x 4 nb), [64,380) -> reaction (79 mb x 4 nb)
  const int bid = blockIdx.x;
  const int z = (bid >= 64) ? 1 : 0;
  const int t = z ? bid - 64 : bid;
  const int mb = t >> 2;
  const int nb = t & 3;
  const int M = (z == 0) ? NDRUG : NREACT;
  const _Float16* A = (z == 0) ? Adrug : Areac;
  const _Float16* B = (z == 0) ? BL : BR;
  _Float16* C = (z == 0) ? Hd : Hr;
  const bool has_bias = (z == 0);
  const int K = HIDDEN, N = HIDDEN;

  __shared__ _Float16 As[BM * BK];
  __shared__ _Float16 Bs[BN * BK];

  const int tid = threadIdx.x;
  const int lane = tid & 63;
  const int wid = tid >> 6;
  const int wm = wid >> 1;
  const int wn = wid & 1;

  f32x4 acc[4][4];
#pragma unroll
  for (int i = 0; i < 4; ++i)
#pragma unroll
    for (int j = 0; j < 4; ++j) acc[i][j] = (f32x4){0.f, 0.f, 0.f, 0.f};

  const int row0 = mb * BM;
  const int col0 = nb * BN;
  const int srow = lane >> 2;
  const int scol = (lane & 3) * 8;

  for (int kt = 0; kt < K; kt += BK) {
#pragma unroll
    for (int i = 0; i < 2; ++i) {
      int rA = row0 + wid * 32 + i * 16 + srow;
      rA = rA < M ? rA : M - 1;
      const _Float16* gA = A + (size_t)rA * K + kt + scol;
      _Float16* lA = As + (wid * 32 + i * 16) * BK;
      __builtin_amdgcn_global_load_lds(
          (const __attribute__((address_space(1))) void*)gA,
          (__attribute__((address_space(3))) void*)lA, 16, 0, 0);
      int rB = col0 + wid * 32 + i * 16 + srow;
      const _Float16* gB = B + (size_t)rB * K + kt + scol;
      _Float16* lB = Bs + (wid * 32 + i * 16) * BK;
      __builtin_amdgcn_global_load_lds(
          (const __attribute__((address_space(1))) void*)gB,
          (__attribute__((address_space(3))) void*)lB, 16, 0, 0);
    }
    __syncthreads();

    const int fr = lane & 15;
    const int kg = (lane >> 4) * 8;
    f16x8 af[4], bfr[4];
#pragma unroll
    for (int mi = 0; mi < 4; ++mi)
      af[mi] = *reinterpret_cast<const f16x8*>(As + (wm * 64 + mi * 16 + fr) * BK + kg);
#pragma unroll
    for (int ni = 0; ni < 4; ++ni)
      bfr[ni] = *reinterpret_cast<const f16x8*>(Bs + (wn * 64 + ni * 16 + fr) * BK + kg);
#pragma unroll
    for (int mi = 0; mi < 4; ++mi)
#pragma unroll
      for (int ni = 0; ni < 4; ++ni)
        acc[mi][ni] = __builtin_amdgcn_mfma_f32_16x16x32_f16(af[mi], bfr[ni], acc[mi][ni], 0, 0, 0);
    __syncthreads();
  }

  const int crow = (lane >> 4) * 4;
  const int ccol = lane & 15;
#pragma unroll
  for (int ni = 0; ni < 4; ++ni) {
    const int gc = col0 + wn * 64 + ni * 16 + ccol;
    const float bv = has_bias ? bias[gc] : 0.0f;
#pragma unroll
    for (int mi = 0; mi < 4; ++mi) {
#pragma unroll
      for (int j = 0; j < 4; ++j) {
        const int gr = row0 + wm * 64 + mi * 16 + crow + j;
        if (gr < M) C[(size_t)gr * N + gc] = (_Float16)(acc[mi][ni][j] + bv);
      }
    }
  }
}

// ---------------- edge kernel v2: in-LDS col sort, Hr rows in LDS, quad work-queue ------
__global__ __launch_bounds__(256) void edge_kernel(
    const _Float16* __restrict__ Hd, const _Float16* __restrict__ Hr,
    const uint64_t* __restrict__ pk, const int* __restrict__ cursor,
    const float* __restrict__ W2, const float* __restrict__ b2,
    float* __restrict__ out)
{
  __shared__ _Float16 hrs[32 * HRSTRIDE];     // 33.3 KB: the bucket's 32 Hr rows (padded)
  __shared__ uint64_t raw[MAXSL];             // 8 KB
  __shared__ uint64_t spk[MAXSL];             // 8 KB col-sorted
  __shared__ int qdesc[MAXSL / 4 + 32];       // quad descriptors
  __shared__ int cnt[32], cb[32], cnt2[32], qoff[32];
  __shared__ int nqs, qhead;

  // bucket->XCD chunked mapping: XCD x owns buckets [x*40, x*40+40)
  const int bid = blockIdx.x;
  const int xcd = bid & 7;
  const int idx = bid >> 3;                 // 0..79
  const int bucket = xcd * 40 + (idx >> 1);
  const int slice = idx & 1;
  const int base = bucket * SLOT;
  const int count = cursor[bucket * CSTRIDE] - base;   // pre-biased cursor
  const int per = (count + BPB2 - 1) / BPB2;
  const int s = slice * per;
  const int e_end0 = (s + per < count) ? s + per : count;
  const int n = (e_end0 > s) ? e_end0 - s : 0;

  const int tid = threadIdx.x;
  const int lane = tid & 63;
  const int li = lane & 15;
  const int wv = tid >> 6;                  // 0..3

  // ---- issue Hr preload: wave wv loads rows [wv*8, wv*8+8), one global_load_lds per row
#pragma unroll
  for (int rr2 = 0; rr2 < 8; ++rr2) {
    int rr = wv * 8 + rr2;
    int gr = bucket * 32 + rr;
    gr = (gr < NREACT) ? gr : NREACT - 1;   // clamp (empty tail buckets)
    const _Float16* src = Hr + (size_t)gr * HIDDEN + lane * 8;
    _Float16* dst = hrs + rr * HRSTRIDE;    // 1040B row stride, 16B aligned
    __builtin_amdgcn_global_load_lds(
        (const __attribute__((address_space(1))) void*)src,
        (__attribute__((address_space(3))) void*)dst, 16, 0, 0);
  }

  // ---- W2 fragment (global, L2-hot): lane covers elems li*8 + 128k
  f16x8 w2v[4];
#pragma unroll
  for (int k = 0; k < 4; ++k) {
    const float* p = W2 + li * 8 + k * 128;
    f16x8 q;
#pragma unroll
    for (int j = 0; j < 8; ++j) q[j] = (_Float16)p[j];
    w2v[k] = q;
  }
  const float bias2 = *b2;
  const f16x8 zero8 = (f16x8)(_Float16)0;

  // ---- in-LDS counting sort by local col (c & 31)
  if (tid < 32) { cnt[tid] = 0; cnt2[tid] = 0; }
  if (tid == 0) qhead = 0;
  __syncthreads();
  for (int i = tid; i < n; i += 256) {
    uint64_t p = pk[base + s + i];
    raw[i] = p;
    atomicAdd(&cnt[(int)(p & 31)], 1);
  }
  __syncthreads();
  if (tid == 0) {
    int acc = 0, qa = 0;
    for (int j = 0; j < 32; ++j) {
      cb[j] = acc; acc += cnt[j];
      qoff[j] = qa; qa += (cnt[j] + 3) >> 2;
    }
    nqs = qa;
  }
  __syncthreads();
  for (int i = tid; i < n; i += 256) {
    uint64_t p = raw[i];
    int lc = (int)(p & 31);
    int lo = atomicAdd(&cnt2[lc], 1);
    spk[cb[lc] + lo] = p;
  }
  __syncthreads();
  if (tid < 32) {
    int j = tid, st = cb[j], len = cnt[j], o = qoff[j];
    for (int q = 0; q < len; q += 4) {
      int cn = len - q; cn = (cn < 4) ? cn : 4;
      qdesc[o++] = j | ((st + q) << 5) | (cn << 16);
    }
  }
  __syncthreads();   // also drains vmcnt -> hrs ready

  // ---- process quads from the shared queue: 16 groups of 16 lanes
  for (;;) {
    int q = 0;
    if (li == 0) q = atomicAdd(&qhead, 1);
    q = __shfl(q, lane & 48);               // broadcast from group leader
    if (q >= nqs) break;
    const int d = qdesc[q];
    const int lc = d & 31;
    const int st = (d >> 5) & 2047;
    const int cn = (d >> 16) & 7;

    // hr fragment from LDS (shared by the quad's 4 edges)
    f16x8 hv[4];
#pragma unroll
    for (int k = 0; k < 4; ++k)
      hv[k] = *reinterpret_cast<const f16x8*>(hrs + lc * HRSTRIDE + li * 8 + k * 128);

    const _Float16* hd[4];
    int si[4];
#pragma unroll
    for (int j = 0; j < 4; ++j) {
      int jj = (j < cn) ? j : cn - 1;
      uint64_t p = spk[st + jj];
      si[j] = (int)(p >> 25);
      hd[j] = Hd + (size_t)((p >> 14) & 0x7FF) * HIDDEN;
    }

    float acc[4] = {0.f, 0.f, 0.f, 0.f};
#pragma unroll
    for (int k = 0; k < 4; ++k) {
      const int o = li * 8 + k * 128;
      f16x8 vd[4];
#pragma unroll
      for (int j = 0; j < 4; ++j)
        vd[j] = *reinterpret_cast<const f16x8*>(hd[j] + o);
#pragma unroll
      for (int j = 0; j < 4; ++j) {
        f16x8 t = __builtin_elementwise_max(vd[j] + hv[k], zero8);
#if defined(HAVE_FDOT2)
#pragma unroll
        for (int qq = 0; qq < 4; ++qq) {
          f16x2 wp = {w2v[k][2 * qq], w2v[k][2 * qq + 1]};
          f16x2 sp = {t[2 * qq], t[2 * qq + 1]};
          acc[j] = __builtin_amdgcn_fdot2(sp, wp, acc[j], false);
        }
#else
#pragma unroll
        for (int qq = 0; qq < 8; ++qq)
          acc[j] += (float)t[qq] * (float)w2v[k][qq];
#endif
      }
    }
#pragma unroll
    for (int off = 8; off >= 1; off >>= 1) {
#pragma unroll
      for (int j = 0; j < 4; ++j) acc[j] += __shfl_xor(acc[j], off);
    }
    if (li == 0) {
      for (int j = 0; j < cn; ++j) out[si[j]] = acc[j] + bias2;
    }
  }
}

extern "C" void kernel_launch(void* const* d_in, const int* in_sizes, int n_in,
                              void* d_out, int out_size, void* d_ws, size_t ws_size,
                              hipStream_t stream) {
  const float* z_drug  = (const float*)d_in[0];
  const float* z_react = (const float*)d_in[1];
  const int*   row     = (const int*)d_in[2];
  const int*   col     = (const int*)d_in[3];
  const float* W1      = (const float*)d_in[4];
  const float* b1      = (const float*)d_in[5];
  const float* W2      = (const float*)d_in[6];
  const float* b2      = (const float*)d_in[7];
  float* out = (float*)d_out;

  char* ws = (char*)d_ws;
  size_t off = 0;
  auto alloc = [&](size_t bytes) {
    void* p = ws + off;
    off += (bytes + 255) & ~(size_t)255;
    return p;
  };
  _Float16* zd_f = (_Float16*)alloc((size_t)NDRUG * HIDDEN * 2);
  _Float16* zr_f = (_Float16*)alloc((size_t)NREACT * HIDDEN * 2);
  _Float16* wl_f = (_Float16*)alloc((size_t)HIDDEN * HIDDEN * 2);
  _Float16* wr_f = (_Float16*)alloc((size_t)HIDDEN * HIDDEN * 2);
  _Float16* Hd   = (_Float16*)alloc((size_t)NDRUG * HIDDEN * 2);
  _Float16* Hr   = (_Float16*)alloc((size_t)NREACT * HIDDEN * 2);
  int*      cursor = (int*)alloc((size_t)NBKT * CSTRIDE * 4);       // 20 KB padded
  uint64_t* pk     = (uint64_t*)alloc((size_t)NBKT * SLOT * 8);     // 5.2 MB

  init_cursor<<<2, 256, 0, stream>>>(cursor);
  setup_kernel<<<1024 + NSCAT, 256, 0, stream>>>(z_drug, z_react, W1, row, col,
                                                 zd_f, zr_f, wl_f, wr_f, cursor, pk);
  gemm_bt<<<380, 256, 0, stream>>>(zd_f, zr_f, wl_f, wr_f, b1, Hd, Hr);
  edge_kernel<<<EBLK, 256, 0, stream>>>(Hd, Hr, pk, cursor, W2, b2, out);
}

// Round 8
// 77.971 us; speedup vs baseline: 2.9896x; 1.0028x over previous
//
#include <hip/hip_runtime.h>
#include <stdint.h>

#define HIDDEN 512
#define NDRUG 2000
#define NREACT 10000
#define NEDGE 400000

// bucketed near-sort: 313 used buckets x 32 cols each (c>>5), padded to 320
#define NBKT 320
#define SLOT 2048                 // capacity per bucket (mean ~1280, sigma ~36; +21 sigma)
#define CSTRIDE 16                // cursor padded to 1 int per 64B cache line
#define NSCAT 128                 // scatter blocks (LDS-aggregated)
#define EPB ((NEDGE + NSCAT - 1) / NSCAT)   // 3125 edges per scatter block

// edge kernel v3: 2 blocks per bucket, 512 threads, in-LDS col sort + Hr in LDS
#define BPB2 2
#define EBLK (NBKT * BPB2)        // 640
#define MAXSL 1024                // max slice entries = ceil(SLOT/BPB2)
#define HRSTRIDE 520              // f16 elems per LDS hr row (512 + 8 pad)
#define ETHREADS 512

typedef __attribute__((ext_vector_type(8))) _Float16 f16x8;
typedef __attribute__((ext_vector_type(2))) _Float16 f16x2;
typedef __attribute__((ext_vector_type(4))) float f32x4;
typedef __attribute__((ext_vector_type(4))) float float4v;
typedef __attribute__((ext_vector_type(4))) _Float16 f16x4;

#if defined(__has_builtin)
#if __has_builtin(__builtin_amdgcn_fdot2)
#define HAVE_FDOT2 1
#endif
#endif

// ---------------- init padded cursors: cursor[b*CSTRIDE] = b*SLOT ----------------
__global__ __launch_bounds__(256) void init_cursor(int* __restrict__ cursor) {
  int i = blockIdx.x * blockDim.x + threadIdx.x;
  if (i < NBKT) cursor[i * CSTRIDE] = i * SLOT;
}

// ---------------- fused setup: cast zd, cast zr, split W1, LDS-aggregated bucket scatter ----
// block partition: [0,128) zd | [128,768) zr | [768,1024) W1 | [1024,1024+NSCAT) scatter
__global__ __launch_bounds__(256) void setup_kernel(
    const float* __restrict__ z_drug, const float* __restrict__ z_react,
    const float* __restrict__ W1,
    const int* __restrict__ row, const int* __restrict__ col,
    _Float16* __restrict__ zd_f, _Float16* __restrict__ zr_f,
    _Float16* __restrict__ WL, _Float16* __restrict__ WR,
    int* __restrict__ cursor, uint64_t* __restrict__ pk)
{
  __shared__ int lhist[NBKT];
  __shared__ int lbase[NBKT];
  const int b = blockIdx.x;
  const int tid = threadIdx.x;
  if (b < 128) {
    const int nth = 128 * 256;
    const int NQ = NDRUG * HIDDEN / 4;
    for (int i = b * 256 + tid; i < NQ; i += nth) {
      float4v v = *reinterpret_cast<const float4v*>(z_drug + (size_t)i * 4);
      f16x4 q; q[0]=(_Float16)v[0]; q[1]=(_Float16)v[1]; q[2]=(_Float16)v[2]; q[3]=(_Float16)v[3];
      *reinterpret_cast<f16x4*>(zd_f + (size_t)i * 4) = q;
    }
  } else if (b < 768) {
    const int nth = 640 * 256;
    const int NQ = NREACT * HIDDEN / 4;
    for (int i = (b - 128) * 256 + tid; i < NQ; i += nth) {
      float4v v = *reinterpret_cast<const float4v*>(z_react + (size_t)i * 4);
      f16x4 q; q[0]=(_Float16)v[0]; q[1]=(_Float16)v[1]; q[2]=(_Float16)v[2]; q[3]=(_Float16)v[3];
      *reinterpret_cast<f16x4*>(zr_f + (size_t)i * 4) = q;
    }
  } else if (b < 1024) {
    const int nth = 256 * 256;
    const int NQ = HIDDEN * 2 * HIDDEN / 4;
    for (int i = (b - 768) * 256 + tid; i < NQ; i += nth) {
      int e = i * 4;
      int o = e >> 10, j = e & 1023;
      float4v v = *reinterpret_cast<const float4v*>(W1 + e);
      f16x4 q; q[0]=(_Float16)v[0]; q[1]=(_Float16)v[1]; q[2]=(_Float16)v[2]; q[3]=(_Float16)v[3];
      if (j < HIDDEN) *reinterpret_cast<f16x4*>(WL + o * HIDDEN + j) = q;
      else            *reinterpret_cast<f16x4*>(WR + o * HIDDEN + (j - HIDDEN)) = q;
    }
  } else {
    // LDS-aggregated bucket scatter. Block handles edges [e0, e1).
    const int sb = b - 1024;
    const int e0 = sb * EPB;
    const int e1 = (e0 + EPB < NEDGE) ? e0 + EPB : NEDGE;
    for (int i = tid; i < NBKT; i += 256) lhist[i] = 0;
    __syncthreads();
    for (int e = e0 + tid; e < e1; e += 256)
      atomicAdd(&lhist[col[e] >> 5], 1);
    __syncthreads();
    for (int i = tid; i < NBKT; i += 256) {
      int cnt = lhist[i];
      lbase[i] = cnt ? atomicAdd(&cursor[i * CSTRIDE], cnt) : 0;  // reserve range (padded line)
      lhist[i] = 0;                                               // reuse as local offset
    }
    __syncthreads();
    for (int e = e0 + tid; e < e1; e += 256) {
      int c = col[e];
      int r = row[e];
      int bkt = c >> 5;
      int lo = atomicAdd(&lhist[bkt], 1);
      pk[lbase[bkt] + lo] = ((uint64_t)e << 25) | ((uint64_t)r << 14) | (uint64_t)c;
    }
  }
}

// ---------------- f16 MFMA GEMM, C[m][n] = sum_k A[m][k]*B[n][k] (+bias[n]) ----------------
#define BM 128
#define BN 128
#define BK 32

__global__ __launch_bounds__(256) void gemm_bt(
    const _Float16* __restrict__ Adrug, const _Float16* __restrict__ Areac,
    const _Float16* __restrict__ BL, const _Float16* __restrict__ BR,
    const float* __restrict__ bias,
    _Float16* __restrict__ Hd, _Float16* __restrict__ Hr)
{
  // flat grid: [0,64) -> drug panel (16 mb x 4 nb), [64,380) -> reaction (79 mb x 4 nb)
  const int bid = blockIdx.x;
  const int z = (bid >= 64) ? 1 : 0;
  const int t = z ? bid - 64 : bid;
  const int mb = t >> 2;
  const int nb = t & 3;
  const int M = (z == 0) ? NDRUG : NREACT;
  const _Float16* A = (z == 0) ? Adrug : Areac;
  const _Float16* B = (z == 0) ? BL : BR;
  _Float16* C = (z == 0) ? Hd : Hr;
  const bool has_bias = (z == 0);
  const int K = HIDDEN, N = HIDDEN;

  __shared__ _Float16 As[BM * BK];
  __shared__ _Float16 Bs[BN * BK];

  const int tid = threadIdx.x;
  const int lane = tid & 63;
  const int wid = tid >> 6;
  const int wm = wid >> 1;
  const int wn = wid & 1;

  f32x4 acc[4][4];
#pragma unroll
  for (int i = 0; i < 4; ++i)
#pragma unroll
    for (int j = 0; j < 4; ++j) acc[i][j] = (f32x4){0.f, 0.f, 0.f, 0.f};

  const int row0 = mb * BM;
  const int col0 = nb * BN;
  const int srow = lane >> 2;
  const int scol = (lane & 3) * 8;

  for (int kt = 0; kt < K; kt += BK) {
#pragma unroll
    for (int i = 0; i < 2; ++i) {
      int rA = row0 + wid * 32 + i * 16 + srow;
      rA = rA < M ? rA : M - 1;
      const _Float16* gA = A + (size_t)rA * K + kt + scol;
      _Float16* lA = As + (wid * 32 + i * 16) * BK;
      __builtin_amdgcn_global_load_lds(
          (const __attribute__((address_space(1))) void*)gA,
          (__attribute__((address_space(3))) void*)lA, 16, 0, 0);
      int rB = col0 + wid * 32 + i * 16 + srow;
      const _Float16* gB = B + (size_t)rB * K + kt + scol;
      _Float16* lB = Bs + (wid * 32 + i * 16) * BK;
      __builtin_amdgcn_global_load_lds(
          (const __attribute__((address_space(1))) void*)gB,
          (__attribute__((address_space(3))) void*)lB, 16, 0, 0);
    }
    __syncthreads();

    const int fr = lane & 15;
    const int kg = (lane >> 4) * 8;
    f16x8 af[4], bfr[4];
#pragma unroll
    for (int mi = 0; mi < 4; ++mi)
      af[mi] = *reinterpret_cast<const f16x8*>(As + (wm * 64 + mi * 16 + fr) * BK + kg);
#pragma unroll
    for (int ni = 0; ni < 4; ++ni)
      bfr[ni] = *reinterpret_cast<const f16x8*>(Bs + (wn * 64 + ni * 16 + fr) * BK + kg);
#pragma unroll
    for (int mi = 0; mi < 4; ++mi)
#pragma unroll
      for (int ni = 0; ni < 4; ++ni)
        acc[mi][ni] = __builtin_amdgcn_mfma_f32_16x16x32_f16(af[mi], bfr[ni], acc[mi][ni], 0, 0, 0);
    __syncthreads();
  }

  const int crow = (lane >> 4) * 4;
  const int ccol = lane & 15;
#pragma unroll
  for (int ni = 0; ni < 4; ++ni) {
    const int gc = col0 + wn * 64 + ni * 16 + ccol;
    const float bv = has_bias ? bias[gc] : 0.0f;
#pragma unroll
    for (int mi = 0; mi < 4; ++mi) {
#pragma unroll
      for (int j = 0; j < 4; ++j) {
        const int gr = row0 + wm * 64 + mi * 16 + crow + j;
        if (gr < M) C[(size_t)gr * N + gc] = (_Float16)(acc[mi][ni][j] + bv);
      }
    }
  }
}

// ---------------- edge kernel v3: 512 thr, in-LDS col sort, Hr in LDS, vd prefetch ------
__global__ __launch_bounds__(ETHREADS) void edge_kernel(
    const _Float16* __restrict__ Hd, const _Float16* __restrict__ Hr,
    const uint64_t* __restrict__ pk, const int* __restrict__ cursor,
    const float* __restrict__ W2, const float* __restrict__ b2,
    float* __restrict__ out)
{
  __shared__ _Float16 hrs[32 * HRSTRIDE];     // 33.3 KB: the bucket's 32 Hr rows (padded)
  __shared__ uint64_t raw[MAXSL];             // 8 KB
  __shared__ uint64_t spk[MAXSL];             // 8 KB col-sorted
  __shared__ int qdesc[MAXSL / 4 + 32];       // quad descriptors
  __shared__ int cnt[32], cb[32], cnt2[32], qoff[32];
  __shared__ int nqs, qhead;

  // bucket->XCD chunked mapping: XCD x owns buckets [x*40, x*40+40)
  const int bid = blockIdx.x;
  const int xcd = bid & 7;
  const int idx = bid >> 3;                 // 0..79
  const int bucket = xcd * 40 + (idx >> 1);
  const int slice = idx & 1;
  const int base = bucket * SLOT;
  const int count = cursor[bucket * CSTRIDE] - base;   // pre-biased cursor
  const int per = (count + BPB2 - 1) / BPB2;
  const int s = slice * per;
  const int e_end0 = (s + per < count) ? s + per : count;
  const int n = (e_end0 > s) ? e_end0 - s : 0;

  const int tid = threadIdx.x;
  const int lane = tid & 63;
  const int li = lane & 15;
  const int wv = tid >> 6;                  // 0..7

  // ---- issue Hr preload: wave wv loads rows [wv*4, wv*4+4), one global_load_lds per row
#pragma unroll
  for (int rr2 = 0; rr2 < 4; ++rr2) {
    int rr = wv * 4 + rr2;
    int gr = bucket * 32 + rr;
    gr = (gr < NREACT) ? gr : NREACT - 1;   // clamp (empty tail buckets)
    const _Float16* src = Hr + (size_t)gr * HIDDEN + lane * 8;
    _Float16* dst = hrs + rr * HRSTRIDE;    // 1040B row stride, 16B aligned
    __builtin_amdgcn_global_load_lds(
        (const __attribute__((address_space(1))) void*)src,
        (__attribute__((address_space(3))) void*)dst, 16, 0, 0);
  }

  // ---- W2 fragment (global, L2-hot): lane covers elems li*8 + 128k
  f16x8 w2v[4];
#pragma unroll
  for (int k = 0; k < 4; ++k) {
    const float* p = W2 + li * 8 + k * 128;
    f16x8 q;
#pragma unroll
    for (int j = 0; j < 8; ++j) q[j] = (_Float16)p[j];
    w2v[k] = q;
  }
  const float bias2 = *b2;
  const f16x8 zero8 = (f16x8)(_Float16)0;

  // ---- in-LDS counting sort by local col (c & 31)
  if (tid < 32) { cnt[tid] = 0; cnt2[tid] = 0; }
  if (tid == 0) qhead = 0;
  __syncthreads();
  for (int i = tid; i < n; i += ETHREADS) {
    uint64_t p = pk[base + s + i];
    raw[i] = p;
    atomicAdd(&cnt[(int)(p & 31)], 1);
  }
  __syncthreads();
  if (tid == 0) {
    int acc = 0, qa = 0;
    for (int j = 0; j < 32; ++j) {
      cb[j] = acc; acc += cnt[j];
      qoff[j] = qa; qa += (cnt[j] + 3) >> 2;
    }
    nqs = qa;
  }
  __syncthreads();
  for (int i = tid; i < n; i += ETHREADS) {
    uint64_t p = raw[i];
    int lc = (int)(p & 31);
    int lo = atomicAdd(&cnt2[lc], 1);
    spk[cb[lc] + lo] = p;
  }
  __syncthreads();
  if (tid < 32) {
    int j = tid, st = cb[j], len = cnt[j], o = qoff[j];
    for (int q = 0; q < len; q += 4) {
      int cn = len - q; cn = (cn < 4) ? cn : 4;
      qdesc[o++] = j | ((st + q) << 5) | (cn << 16);
    }
  }
  __syncthreads();   // also drains vmcnt -> hrs ready

  // ---- process quads from the shared queue: 32 groups of 16 lanes
  for (;;) {
    int q = 0;
    if (li == 0) q = atomicAdd(&qhead, 1);
    q = __shfl(q, lane & 48);               // broadcast from group leader
    if (q >= nqs) break;
    const int d = qdesc[q];
    const int lc = d & 31;
    const int st = (d >> 5) & 2047;
    const int cn = (d >> 16) & 7;

    const _Float16* hd[4];
    int si[4];
#pragma unroll
    for (int j = 0; j < 4; ++j) {
      int jj = (j < cn) ? j : cn - 1;
      uint64_t p = spk[st + jj];
      si[j] = (int)(p >> 25);
      hd[j] = Hd + (size_t)((p >> 14) & 0x7FF) * HIDDEN;
    }

    // prefetch the whole quad working set: 4 edges x 4 k-steps (64 VGPRs)
    f16x8 vd[4][4];
#pragma unroll
    for (int j = 0; j < 4; ++j)
#pragma unroll
      for (int k = 0; k < 4; ++k)
        vd[j][k] = *reinterpret_cast<const f16x8*>(hd[j] + li * 8 + k * 128);

    // hr fragment from LDS (shared by the quad's 4 edges)
    f16x8 hv[4];
#pragma unroll
    for (int k = 0; k < 4; ++k)
      hv[k] = *reinterpret_cast<const f16x8*>(hrs + lc * HRSTRIDE + li * 8 + k * 128);

    float acc[4] = {0.f, 0.f, 0.f, 0.f};
#pragma unroll
    for (int j = 0; j < 4; ++j) {
#pragma unroll
      for (int k = 0; k < 4; ++k) {
        f16x8 t = __builtin_elementwise_max(vd[j][k] + hv[k], zero8);
#if defined(HAVE_FDOT2)
#pragma unroll
        for (int qq = 0; qq < 4; ++qq) {
          f16x2 wp = {w2v[k][2 * qq], w2v[k][2 * qq + 1]};
          f16x2 sp = {t[2 * qq], t[2 * qq + 1]};
          acc[j] = __builtin_amdgcn_fdot2(sp, wp, acc[j], false);
        }
#else
#pragma unroll
        for (int qq = 0; qq < 8; ++qq)
          acc[j] += (float)t[qq] * (float)w2v[k][qq];
#endif
      }
    }
#pragma unroll
    for (int off = 8; off >= 1; off >>= 1) {
#pragma unroll
      for (int j = 0; j < 4; ++j) acc[j] += __shfl_xor(acc[j], off);
    }
    if (li == 0) {
      for (int j = 0; j < cn; ++j) out[si[j]] = acc[j] + bias2;
    }
  }
}

extern "C" void kernel_launch(void* const* d_in, const int* in_sizes, int n_in,
                              void* d_out, int out_size, void* d_ws, size_t ws_size,
                              hipStream_t stream) {
  const float* z_drug  = (const float*)d_in[0];
  const float* z_react = (const float*)d_in[1];
  const int*   row     = (const int*)d_in[2];
  const int*   col     = (const int*)d_in[3];
  const float* W1      = (const float*)d_in[4];
  const float* b1      = (const float*)d_in[5];
  const float* W2      = (const float*)d_in[6];
  const float* b2      = (const float*)d_in[7];
  float* out = (float*)d_out;

  char* ws = (char*)d_ws;
  size_t off = 0;
  auto alloc = [&](size_t bytes) {
    void* p = ws + off;
    off += (bytes + 255) & ~(size_t)255;
    return p;
  };
  _Float16* zd_f = (_Float16*)alloc((size_t)NDRUG * HIDDEN * 2);
  _Float16* zr_f = (_Float16*)alloc((size_t)NREACT * HIDDEN * 2);
  _Float16* wl_f = (_Float16*)alloc((size_t)HIDDEN * HIDDEN * 2);
  _Float16* wr_f = (_Float16*)alloc((size_t)HIDDEN * HIDDEN * 2);
  _Float16* Hd   = (_Float16*)alloc((size_t)NDRUG * HIDDEN * 2);
  _Float16* Hr   = (_Float16*)alloc((size_t)NREACT * HIDDEN * 2);
  int*      cursor = (int*)alloc((size_t)NBKT * CSTRIDE * 4);       // 20 KB padded
  uint64_t* pk     = (uint64_t*)alloc((size_t)NBKT * SLOT * 8);     // 5.2 MB

  init_cursor<<<2, 256, 0, stream>>>(cursor);
  setup_kernel<<<1024 + NSCAT, 256, 0, stream>>>(z_drug, z_react, W1, row, col,
                                                 zd_f, zr_f, wl_f, wr_f, cursor, pk);
  gemm_bt<<<380, 256, 0, stream>>>(zd_f, zr_f, wl_f, wr_f, b1, Hd, Hr);
  edge_kernel<<<EBLK, ETHREADS, 0, stream>>>(Hd, Hr, pk, cursor, W2, b2, out);
}

// Round 9
// 67.472 us; speedup vs baseline: 3.4548x; 1.1556x over previous
//
#include <hip/hip_runtime.h>
#include <stdint.h>

#define HIDDEN 512
#define NDRUG 2000
#define NREACT 10000
#define NEDGE 400000

// bucketed near-sort: 313 used buckets x 32 cols each (c>>5), padded to 320
#define NBKT 320
#define SLOT 2048                 // capacity per bucket (mean ~1280, sigma ~36; +21 sigma)
#define CSTRIDE 16                // cursor padded to 1 int per 64B cache line
#define NSCAT 128                 // scatter blocks (LDS-aggregated)
#define EPB ((NEDGE + NSCAT - 1) / NSCAT)   // 3125 edges per scatter block

// edge kernel: 2 blocks per bucket, 512 threads, in-LDS col sort + Hr in LDS
#define BPB2 2
#define EBLK (NBKT * BPB2)        // 640
#define MAXSL 1024                // max slice entries = ceil(SLOT/BPB2)
#define HRSTRIDE 520              // f16 elems per LDS hr row (512 + 8 pad)
#define ETHREADS 512

#define GEMMBLKS 380              // gemm blocks in fused gemm_scatter grid

typedef __attribute__((ext_vector_type(8))) _Float16 f16x8;
typedef __attribute__((ext_vector_type(2))) _Float16 f16x2;
typedef __attribute__((ext_vector_type(4))) float f32x4;
typedef __attribute__((ext_vector_type(4))) float float4v;
typedef __attribute__((ext_vector_type(4))) _Float16 f16x4;

#if defined(__has_builtin)
#if __has_builtin(__builtin_amdgcn_fdot2)
#define HAVE_FDOT2 1
#endif
#endif

// ---------------- prep: cast zd, cast zr, split W1, init cursors ----------------
// block partition: [0,128) zd | [128,768) zr | [768,1024) W1 | [1024,1026) cursor init
__global__ __launch_bounds__(256) void prep_kernel(
    const float* __restrict__ z_drug, const float* __restrict__ z_react,
    const float* __restrict__ W1,
    _Float16* __restrict__ zd_f, _Float16* __restrict__ zr_f,
    _Float16* __restrict__ WL, _Float16* __restrict__ WR,
    int* __restrict__ cursor)
{
  const int b = blockIdx.x;
  const int tid = threadIdx.x;
  if (b < 128) {
    const int nth = 128 * 256;
    const int NQ = NDRUG * HIDDEN / 4;
    for (int i = b * 256 + tid; i < NQ; i += nth) {
      float4v v = *reinterpret_cast<const float4v*>(z_drug + (size_t)i * 4);
      f16x4 q; q[0]=(_Float16)v[0]; q[1]=(_Float16)v[1]; q[2]=(_Float16)v[2]; q[3]=(_Float16)v[3];
      *reinterpret_cast<f16x4*>(zd_f + (size_t)i * 4) = q;
    }
  } else if (b < 768) {
    const int nth = 640 * 256;
    const int NQ = NREACT * HIDDEN / 4;
    for (int i = (b - 128) * 256 + tid; i < NQ; i += nth) {
      float4v v = *reinterpret_cast<const float4v*>(z_react + (size_t)i * 4);
      f16x4 q; q[0]=(_Float16)v[0]; q[1]=(_Float16)v[1]; q[2]=(_Float16)v[2]; q[3]=(_Float16)v[3];
      *reinterpret_cast<f16x4*>(zr_f + (size_t)i * 4) = q;
    }
  } else if (b < 1024) {
    const int nth = 256 * 256;
    const int NQ = HIDDEN * 2 * HIDDEN / 4;
    for (int i = (b - 768) * 256 + tid; i < NQ; i += nth) {
      int e = i * 4;
      int o = e >> 10, j = e & 1023;
      float4v v = *reinterpret_cast<const float4v*>(W1 + e);
      f16x4 q; q[0]=(_Float16)v[0]; q[1]=(_Float16)v[1]; q[2]=(_Float16)v[2]; q[3]=(_Float16)v[3];
      if (j < HIDDEN) *reinterpret_cast<f16x4*>(WL + o * HIDDEN + j) = q;
      else            *reinterpret_cast<f16x4*>(WR + o * HIDDEN + (j - HIDDEN)) = q;
    }
  } else {
    int i = (b - 1024) * 256 + tid;
    if (i < NBKT) cursor[i * CSTRIDE] = i * SLOT;
  }
}

// ---------------- fused gemm + scatter ----------------
// blocks [0,380): f16 MFMA GEMM; blocks [380,380+NSCAT): LDS-aggregated bucket scatter
#define BM 128
#define BN 128
#define BK 32

__global__ __launch_bounds__(256) void gemm_scatter(
    const _Float16* __restrict__ Adrug, const _Float16* __restrict__ Areac,
    const _Float16* __restrict__ BL, const _Float16* __restrict__ BR,
    const float* __restrict__ bias,
    const int* __restrict__ row, const int* __restrict__ col,
    _Float16* __restrict__ Hd, _Float16* __restrict__ Hr,
    int* __restrict__ cursor, uint64_t* __restrict__ pk)
{
  __shared__ _Float16 As[BM * BK];
  __shared__ _Float16 Bs[BN * BK];
  __shared__ int lhist[NBKT];
  __shared__ int lbase[NBKT];

  const int bid = blockIdx.x;
  const int tid = threadIdx.x;

  if (bid >= GEMMBLKS) {
    // ---- scatter branch: block handles edges [e0, e1)
    const int sb = bid - GEMMBLKS;
    const int e0 = sb * EPB;
    const int e1 = (e0 + EPB < NEDGE) ? e0 + EPB : NEDGE;
    for (int i = tid; i < NBKT; i += 256) lhist[i] = 0;
    __syncthreads();
    for (int e = e0 + tid; e < e1; e += 256)
      atomicAdd(&lhist[col[e] >> 5], 1);
    __syncthreads();
    for (int i = tid; i < NBKT; i += 256) {
      int cnt = lhist[i];
      lbase[i] = cnt ? atomicAdd(&cursor[i * CSTRIDE], cnt) : 0;  // reserve range (padded line)
      lhist[i] = 0;                                               // reuse as local offset
    }
    __syncthreads();
    for (int e = e0 + tid; e < e1; e += 256) {
      int c = col[e];
      int r = row[e];
      int bkt = c >> 5;
      int lo = atomicAdd(&lhist[bkt], 1);
      pk[lbase[bkt] + lo] = ((uint64_t)e << 25) | ((uint64_t)r << 14) | (uint64_t)c;
    }
    return;
  }

  // ---- gemm branch: flat [0,64) -> drug (16 mb x 4 nb), [64,380) -> reaction (79 mb x 4 nb)
  const int z = (bid >= 64) ? 1 : 0;
  const int t = z ? bid - 64 : bid;
  const int mb = t >> 2;
  const int nb = t & 3;
  const int M = (z == 0) ? NDRUG : NREACT;
  const _Float16* A = (z == 0) ? Adrug : Areac;
  const _Float16* B = (z == 0) ? BL : BR;
  _Float16* C = (z == 0) ? Hd : Hr;
  const bool has_bias = (z == 0);
  const int K = HIDDEN, N = HIDDEN;

  const int lane = tid & 63;
  const int wid = tid >> 6;
  const int wm = wid >> 1;
  const int wn = wid & 1;

  f32x4 acc[4][4];
#pragma unroll
  for (int i = 0; i < 4; ++i)
#pragma unroll
    for (int j = 0; j < 4; ++j) acc[i][j] = (f32x4){0.f, 0.f, 0.f, 0.f};

  const int row0 = mb * BM;
  const int col0 = nb * BN;
  const int srow = lane >> 2;
  const int scol = (lane & 3) * 8;

  for (int kt = 0; kt < K; kt += BK) {
#pragma unroll
    for (int i = 0; i < 2; ++i) {
      int rA = row0 + wid * 32 + i * 16 + srow;
      rA = rA < M ? rA : M - 1;
      const _Float16* gA = A + (size_t)rA * K + kt + scol;
      _Float16* lA = As + (wid * 32 + i * 16) * BK;
      __builtin_amdgcn_global_load_lds(
          (const __attribute__((address_space(1))) void*)gA,
          (__attribute__((address_space(3))) void*)lA, 16, 0, 0);
      int rB = col0 + wid * 32 + i * 16 + srow;
      const _Float16* gB = B + (size_t)rB * K + kt + scol;
      _Float16* lB = Bs + (wid * 32 + i * 16) * BK;
      __builtin_amdgcn_global_load_lds(
          (const __attribute__((address_space(1))) void*)gB,
          (__attribute__((address_space(3))) void*)lB, 16, 0, 0);
    }
    __syncthreads();

    const int fr = lane & 15;
    const int kg = (lane >> 4) * 8;
    f16x8 af[4], bfr[4];
#pragma unroll
    for (int mi = 0; mi < 4; ++mi)
      af[mi] = *reinterpret_cast<const f16x8*>(As + (wm * 64 + mi * 16 + fr) * BK + kg);
#pragma unroll
    for (int ni = 0; ni < 4; ++ni)
      bfr[ni] = *reinterpret_cast<const f16x8*>(Bs + (wn * 64 + ni * 16 + fr) * BK + kg);
#pragma unroll
    for (int mi = 0; mi < 4; ++mi)
#pragma unroll
      for (int ni = 0; ni < 4; ++ni)
        acc[mi][ni] = __builtin_amdgcn_mfma_f32_16x16x32_f16(af[mi], bfr[ni], acc[mi][ni], 0, 0, 0);
    __syncthreads();
  }

  const int crow = (lane >> 4) * 4;
  const int ccol = lane & 15;
#pragma unroll
  for (int ni = 0; ni < 4; ++ni) {
    const int gc = col0 + wn * 64 + ni * 16 + ccol;
    const float bv = has_bias ? bias[gc] : 0.0f;
#pragma unroll
    for (int mi = 0; mi < 4; ++mi) {
#pragma unroll
      for (int j = 0; j < 4; ++j) {
        const int gr = row0 + wm * 64 + mi * 16 + crow + j;
        if (gr < M) C[(size_t)gr * N + gc] = (_Float16)(acc[mi][ni][j] + bv);
      }
    }
  }
}

// ---------------- edge kernel: 512 thr, in-LDS col sort, Hr in LDS, STATIC quad map ----
__global__ __launch_bounds__(ETHREADS) void edge_kernel(
    const _Float16* __restrict__ Hd, const _Float16* __restrict__ Hr,
    const uint64_t* __restrict__ pk, const int* __restrict__ cursor,
    const float* __restrict__ W2, const float* __restrict__ b2,
    float* __restrict__ out)
{
  __shared__ _Float16 hrs[32 * HRSTRIDE];     // 33.3 KB: the bucket's 32 Hr rows (padded)
  __shared__ uint64_t raw[MAXSL];             // 8 KB
  __shared__ uint64_t spk[MAXSL];             // 8 KB col-sorted
  __shared__ int qdesc[MAXSL / 4 + 32];       // quad descriptors
  __shared__ int cnt[32], cb[32], cnt2[32], qoff[32];
  __shared__ int nqs;

  // bucket->XCD chunked mapping: XCD x owns buckets [x*40, x*40+40)
  const int bid = blockIdx.x;
  const int xcd = bid & 7;
  const int idx = bid >> 3;                 // 0..79
  const int bucket = xcd * 40 + (idx >> 1);
  const int slice = idx & 1;
  const int base = bucket * SLOT;
  const int count = cursor[bucket * CSTRIDE] - base;   // pre-biased cursor
  const int per = (count + BPB2 - 1) / BPB2;
  const int s = slice * per;
  const int e_end0 = (s + per < count) ? s + per : count;
  const int n = (e_end0 > s) ? e_end0 - s : 0;

  const int tid = threadIdx.x;
  const int lane = tid & 63;
  const int li = lane & 15;
  const int wv = tid >> 6;                  // 0..7
  const int gid = wv * 4 + (lane >> 4);     // 0..31: static group id

  // ---- issue Hr preload: wave wv loads rows [wv*4, wv*4+4), one global_load_lds per row
#pragma unroll
  for (int rr2 = 0; rr2 < 4; ++rr2) {
    int rr = wv * 4 + rr2;
    int gr = bucket * 32 + rr;
    gr = (gr < NREACT) ? gr : NREACT - 1;   // clamp (empty tail buckets)
    const _Float16* src = Hr + (size_t)gr * HIDDEN + lane * 8;
    _Float16* dst = hrs + rr * HRSTRIDE;    // 1040B row stride, 16B aligned
    __builtin_amdgcn_global_load_lds(
        (const __attribute__((address_space(1))) void*)src,
        (__attribute__((address_space(3))) void*)dst, 16, 0, 0);
  }

  // ---- W2 fragment (global, L2-hot): lane covers elems li*8 + 128k
  f16x8 w2v[4];
#pragma unroll
  for (int k = 0; k < 4; ++k) {
    const float* p = W2 + li * 8 + k * 128;
    f16x8 q;
#pragma unroll
    for (int j = 0; j < 8; ++j) q[j] = (_Float16)p[j];
    w2v[k] = q;
  }
  const float bias2 = *b2;
  const f16x8 zero8 = (f16x8)(_Float16)0;

  // ---- in-LDS counting sort by local col (c & 31)
  if (tid < 32) { cnt[tid] = 0; cnt2[tid] = 0; }
  __syncthreads();
  for (int i = tid; i < n; i += ETHREADS) {
    uint64_t p = pk[base + s + i];
    raw[i] = p;
    atomicAdd(&cnt[(int)(p & 31)], 1);
  }
  __syncthreads();
  if (tid == 0) {
    int acc = 0, qa = 0;
    for (int j = 0; j < 32; ++j) {
      cb[j] = acc; acc += cnt[j];
      qoff[j] = qa; qa += (cnt[j] + 3) >> 2;
    }
    nqs = qa;
  }
  __syncthreads();
  for (int i = tid; i < n; i += ETHREADS) {
    uint64_t p = raw[i];
    int lc = (int)(p & 31);
    int lo = atomicAdd(&cnt2[lc], 1);
    spk[cb[lc] + lo] = p;
  }
  __syncthreads();
  if (tid < 32) {
    int j = tid, st = cb[j], len = cnt[j], o = qoff[j];
    for (int q = 0; q < len; q += 4) {
      int cn = len - q; cn = (cn < 4) ? cn : 4;
      qdesc[o++] = j | ((st + q) << 5) | (cn << 16);
    }
  }
  __syncthreads();   // also drains vmcnt -> hrs ready

  // ---- process quads, statically strided: group gid takes quads gid, gid+32, ...
  const int nq = nqs;
  for (int q = gid; q < nq; q += 32) {
    const int d = qdesc[q];
    const int lc = d & 31;
    const int st = (d >> 5) & 2047;
    const int cn = (d >> 16) & 7;

    const _Float16* hd[4];
    int si[4];
#pragma unroll
    for (int j = 0; j < 4; ++j) {
      int jj = (j < cn) ? j : cn - 1;
      uint64_t p = spk[st + jj];
      si[j] = (int)(p >> 25);
      hd[j] = Hd + (size_t)((p >> 14) & 0x7FF) * HIDDEN;
    }

    // prefetch the whole quad working set: 4 edges x 4 k-steps
    f16x8 vd[4][4];
#pragma unroll
    for (int j = 0; j < 4; ++j)
#pragma unroll
      for (int k = 0; k < 4; ++k)
        vd[j][k] = *reinterpret_cast<const f16x8*>(hd[j] + li * 8 + k * 128);

    // hr fragment from LDS (shared by the quad's 4 edges)
    f16x8 hv[4];
#pragma unroll
    for (int k = 0; k < 4; ++k)
      hv[k] = *reinterpret_cast<const f16x8*>(hrs + lc * HRSTRIDE + li * 8 + k * 128);

    float acc[4] = {0.f, 0.f, 0.f, 0.f};
#pragma unroll
    for (int j = 0; j < 4; ++j) {
#pragma unroll
      for (int k = 0; k < 4; ++k) {
        f16x8 t = __builtin_elementwise_max(vd[j][k] + hv[k], zero8);
#if defined(HAVE_FDOT2)
#pragma unroll
        for (int qq = 0; qq < 4; ++qq) {
          f16x2 wp = {w2v[k][2 * qq], w2v[k][2 * qq + 1]};
          f16x2 sp = {t[2 * qq], t[2 * qq + 1]};
          acc[j] = __builtin_amdgcn_fdot2(sp, wp, acc[j], false);
        }
#else
#pragma unroll
        for (int qq = 0; qq < 8; ++qq)
          acc[j] += (float)t[qq] * (float)w2v[k][qq];
#endif
      }
    }
#pragma unroll
    for (int off = 8; off >= 1; off >>= 1) {
#pragma unroll
      for (int j = 0; j < 4; ++j) acc[j] += __shfl_xor(acc[j], off);
    }
    if (li == 0) {
      for (int j = 0; j < cn; ++j) out[si[j]] = acc[j] + bias2;
    }
  }
}

extern "C" void kernel_launch(void* const* d_in, const int* in_sizes, int n_in,
                              void* d_out, int out_size, void* d_ws, size_t ws_size,
                              hipStream_t stream) {
  const float* z_drug  = (const float*)d_in[0];
  const float* z_react = (const float*)d_in[1];
  const int*   row     = (const int*)d_in[2];
  const int*   col     = (const int*)d_in[3];
  const float* W1      = (const float*)d_in[4];
  const float* b1      = (const float*)d_in[5];
  const float* W2      = (const float*)d_in[6];
  const float* b2      = (const float*)d_in[7];
  float* out = (float*)d_out;

  char* ws = (char*)d_ws;
  size_t off = 0;
  auto alloc = [&](size_t bytes) {
    void* p = ws + off;
    off += (bytes + 255) & ~(size_t)255;
    return p;
  };
  _Float16* zd_f = (_Float16*)alloc((size_t)NDRUG * HIDDEN * 2);
  _Float16* zr_f = (_Float16*)alloc((size_t)NREACT * HIDDEN * 2);
  _Float16* wl_f = (_Float16*)alloc((size_t)HIDDEN * HIDDEN * 2);
  _Float16* wr_f = (_Float16*)alloc((size_t)HIDDEN * HIDDEN * 2);
  _Float16* Hd   = (_Float16*)alloc((size_t)NDRUG * HIDDEN * 2);
  _Float16* Hr   = (_Float16*)alloc((size_t)NREACT * HIDDEN * 2);
  int*      cursor = (int*)alloc((size_t)NBKT * CSTRIDE * 4);       // 20 KB padded
  uint64_t* pk     = (uint64_t*)alloc((size_t)NBKT * SLOT * 8);     // 5.2 MB

  prep_kernel<<<1026, 256, 0, stream>>>(z_drug, z_react, W1,
                                        zd_f, zr_f, wl_f, wr_f, cursor);
  gemm_scatter<<<GEMMBLKS + NSCAT, 256, 0, stream>>>(zd_f, zr_f, wl_f, wr_f, b1,
                                                     row, col, Hd, Hr, cursor, pk);
  edge_kernel<<<EBLK, ETHREADS, 0, stream>>>(Hd, Hr, pk, cursor, W2, b2, out);
}